// Round 5
// baseline (4598.812 us; speedup 1.0000x reference)
//
#include <hip/hip_runtime.h>

// Problem constants: T=128, B=64, D=1024, H=1024. fp32 throughout (the
// recurrence is chaotic: per-step gate noise amplifies ~1e3x over 128 steps;
// fp32 order-noise lands at ~4e-3 absmax, bf16 would fail the 2e-2 gate).
#define TT 128
#define BB 64
#define DD 1024
#define HH 1024
#define G4 4096          // 4*H
#define MM (TT*BB)       // 8192 rows of X flattened
#define BH (BB*HH)       // 65536, one timestep of h/out

#define NWG 256          // persistent grid: exactly 1 block per CU

__device__ __forceinline__ float hsig(float x) {
    x += 0.5f;
    return fminf(fmaxf(x, 0.0f), 1.0f);
}
__device__ __forceinline__ float htanh(float x) {
    return fminf(fmaxf(x, -1.0f), 1.0f);
}

// ---------------------------------------------------------------------------
__global__ void zero_bar(unsigned* p) {
    if (threadIdx.x < 2) p[threadIdx.x] = 0u;
}

// ---------------------------------------------------------------------------
// Gx[8192][4096] = X[8192][1024] @ Wx[1024][4096] + bias  (proven, ~810 us)
__global__ __launch_bounds__(256) void gx_gemm(const float* __restrict__ X,
                                               const float* __restrict__ W,
                                               const float* __restrict__ bias,
                                               float* __restrict__ C) {
    __shared__ float As[16][132];
    __shared__ float Bs[16][132];

    const int tid = threadIdx.x;
    const int tx = tid & 15;
    const int ty = tid >> 4;
    const int m0 = blockIdx.y * 128;
    const int n0 = blockIdx.x * 128;

    float acc[8][8] = {};
    float4 ra[2], rb[2];

    #pragma unroll
    for (int i = 0; i < 2; ++i) {
        int f4 = tid + i * 256;
        ra[i] = *(const float4*)(X + (size_t)(m0 + (f4 >> 2)) * DD + (f4 & 3) * 4);
        rb[i] = *(const float4*)(W + (size_t)(f4 >> 5) * G4 + n0 + (f4 & 31) * 4);
    }

    for (int k0 = 0; k0 < DD; k0 += 16) {
        #pragma unroll
        for (int i = 0; i < 2; ++i) {
            int f4 = tid + i * 256;
            int mi = f4 >> 2, kq = f4 & 3;
            As[kq * 4 + 0][mi] = ra[i].x;
            As[kq * 4 + 1][mi] = ra[i].y;
            As[kq * 4 + 2][mi] = ra[i].z;
            As[kq * 4 + 3][mi] = ra[i].w;
            *(float4*)&Bs[f4 >> 5][(f4 & 31) * 4] = rb[i];
        }
        __syncthreads();

        const int kn = (k0 + 16 < DD) ? (k0 + 16) : k0;
        #pragma unroll
        for (int i = 0; i < 2; ++i) {
            int f4 = tid + i * 256;
            ra[i] = *(const float4*)(X + (size_t)(m0 + (f4 >> 2)) * DD + kn + (f4 & 3) * 4);
            rb[i] = *(const float4*)(W + (size_t)(kn + (f4 >> 5)) * G4 + n0 + (f4 & 31) * 4);
        }

        #pragma unroll
        for (int kk = 0; kk < 16; ++kk) {
            float ar[8], br[8];
            *(float4*)&ar[0] = *(const float4*)&As[kk][ty * 4];
            *(float4*)&ar[4] = *(const float4*)&As[kk][64 + ty * 4];
            *(float4*)&br[0] = *(const float4*)&Bs[kk][tx * 4];
            *(float4*)&br[4] = *(const float4*)&Bs[kk][64 + tx * 4];
            #pragma unroll
            for (int i = 0; i < 8; ++i)
                #pragma unroll
                for (int j = 0; j < 8; ++j)
                    acc[i][j] += ar[i] * br[j];
        }
        __syncthreads();
    }

    float bl[8];
    *(float4*)&bl[0] = *(const float4*)(bias + n0 + tx * 4);
    *(float4*)&bl[4] = *(const float4*)(bias + n0 + 64 + tx * 4);
    #pragma unroll
    for (int i = 0; i < 8; ++i) {
        int mrow = m0 + ty * 4 + (i & 3) + 64 * (i >> 2);
        float* crow = C + (size_t)mrow * G4 + n0;
        float4 o1, o2;
        o1.x = acc[i][0] + bl[0]; o1.y = acc[i][1] + bl[1];
        o1.z = acc[i][2] + bl[2]; o1.w = acc[i][3] + bl[3];
        o2.x = acc[i][4] + bl[4]; o2.y = acc[i][5] + bl[5];
        o2.z = acc[i][6] + bl[6]; o2.w = acc[i][7] + bl[7];
        *(float4*)(crow + tx * 4) = o1;
        *(float4*)(crow + 64 + tx * 4) = o2;
    }
}

// ---------------------------------------------------------------------------
// Epoch grid barrier (plain launch; residency guaranteed by 1 block/CU).
// Release: __syncthreads drains all wg stores to L2 (compiler emits
// s_waitcnt vmcnt(0) before s_barrier); thread0's __threadfence does the
// agent-scope L2 writeback; acquire side invalidates L1/L2 before reads.
__device__ __forceinline__ void gbar(unsigned* cnt, unsigned* ep, unsigned& epoch) {
    __syncthreads();
    if (threadIdx.x == 0) {
        __threadfence();
        unsigned old = atomicAdd(cnt, 1u);
        if (old == epoch * NWG + (NWG - 1)) {
            __hip_atomic_store(ep, epoch + 1, __ATOMIC_RELEASE, __HIP_MEMORY_SCOPE_AGENT);
        } else {
            while (__hip_atomic_load(ep, __ATOMIC_ACQUIRE, __HIP_MEMORY_SCOPE_AGENT) < epoch + 1)
                __builtin_amdgcn_s_sleep(2);
        }
        __threadfence();
    }
    epoch++;
    __syncthreads();
}

// ---------------------------------------------------------------------------
// Persistent recurrence, ONE barrier per step.
// Grid 256 wgs = 8 btiles(8 b) x 32 hct(32 hc). wg owns cells (8 b x 32 hc)
// with all 4 gates -> cell fully wg-local, c in a register per thread for
// all 128 steps. Full K=1024 per wg, k-split 16-way ACROSS THREADS (LDS
// reduce, no global partials). Thread (kc=tid>>4, tt=tid&15): 8b x 8gc
// register tile over a 64-k chunk; per 4k: 8 broadcast ds_read_b128 (h) +
// 8 global float4 (Wh, L2-resident slice per XCD) + 256 FMA -> VALU-bound.
// bx = btile*32+hct: the 8 wgs sharing a Wh column-slice share bx%8 (same
// XCD under round-robin) -> slice stays in that XCD's L2 (perf heuristic).
__global__ __launch_bounds__(256, 1) void lstm_persist(const float* __restrict__ Gx,
                                                       const float* __restrict__ Wh,
                                                       float* __restrict__ out,
                                                       unsigned* __restrict__ bar) {
    // union: hs = h-tile [8 b][1032 (1024+pad)] = 8256 floats (phase: FMA)
    //        red = k-split partials [256 thr][34 (32+pad)] = 8704 floats
    __shared__ float smem[8704];
    float* hs  = smem;
    float* red = smem;

    const int tid = threadIdx.x;
    const int btile = blockIdx.x >> 5;     // 0..7
    const int hct   = blockIdx.x & 31;     // 0..31
    const int b0 = btile * 8;

    // matmul thread identity
    const int kc = tid >> 4;               // 0..15 (64-k chunk)
    const int tt = tid & 15;               // 0..15 (8 gate-cols)
    const int gate = tt >> 2;              // 0..3
    const int hq8  = (tt & 3) * 8;         // 8-col group within 32-hc tile
    const float* wbase = Wh + (size_t)(kc * 64) * G4 + gate * HH + hct * 32 + hq8;

    // cell thread identity (fixed all steps -> c lives in creg)
    const int cb   = tid >> 5;             // 0..7 local b
    const int chcm = tid & 31;             // 0..31 local hc
    const size_t cell_g = (size_t)(b0 + cb) * G4 + hct * 32 + chcm;  // into Gx[t]
    const size_t cell_h = (size_t)(b0 + cb) * HH + hct * 32 + chcm;  // into out[t]
    float creg;

    // ---- t = 0: gates = Gx[0] (h0 = c0 = 0)
    {
        const float* gr = Gx + cell_g;
        float ii = hsig(gr[0]);
        float gv = htanh(gr[2 * HH]);
        float oo = hsig(gr[3 * HH]);
        creg = ii * gv;
        out[cell_h] = oo * htanh(creg);
    }

    unsigned epoch = 0;
    unsigned* cnt = bar;
    unsigned* ep  = bar + 1;

    for (int t = 1; t < TT; ++t) {
        gbar(cnt, ep, epoch);              // h(t-1) visible; smem free

        // ---- stage h(t-1)[b0..b0+7][0..1023] -> hs (coalesced, conflict-free)
        const float* hprev = out + (size_t)(t - 1) * BH;
        #pragma unroll
        for (int i = 0; i < 8; ++i) {
            int idx = tid + i * 256;       // 0..2047
            int bi = idx >> 8;
            int q  = idx & 255;
            *(float4*)&hs[bi * 1032 + q * 4] =
                *(const float4*)(hprev + (size_t)(b0 + bi) * HH + q * 4);
        }
        // prefetch this step's Gx gate values (independent of hs)
        const float* gr = Gx + (size_t)t * BB * G4 + cell_g;
        float gi = gr[0];
        float gf = gr[HH];
        float gg = gr[2 * HH];
        float go = gr[3 * HH];
        __syncthreads();

        // ---- FMA: acc[8 b][8 gc] over k in [kc*64, kc*64+64)
        float acc[8][8] = {};
        const float* wp = wbase;
        #pragma unroll 2
        for (int k4 = 0; k4 < 16; ++k4) {
            const int kb = kc * 64 + k4 * 4;
            float4 hv[8];
            #pragma unroll
            for (int bi = 0; bi < 8; ++bi)
                hv[bi] = *(const float4*)&hs[bi * 1032 + kb];
            #pragma unroll
            for (int j = 0; j < 4; ++j) {
                float4 w0 = *(const float4*)(wp);
                float4 w1 = *(const float4*)(wp + 4);
                wp += G4;
                #pragma unroll
                for (int bi = 0; bi < 8; ++bi) {
                    float h = (j == 0) ? hv[bi].x : (j == 1) ? hv[bi].y
                              : (j == 2) ? hv[bi].z : hv[bi].w;
                    acc[bi][0] += h * w0.x;
                    acc[bi][1] += h * w0.y;
                    acc[bi][2] += h * w0.z;
                    acc[bi][3] += h * w0.w;
                    acc[bi][4] += h * w1.x;
                    acc[bi][5] += h * w1.y;
                    acc[bi][6] += h * w1.z;
                    acc[bi][7] += h * w1.w;
                }
            }
        }
        __syncthreads();                   // hs dead; smem becomes red

        float gates[4];                    // reduced i,f,g,o for this cell
        // ---- two half-reductions (b 0..3, then b 4..7); 17 KB each, padded
        #pragma unroll
        for (int half = 0; half < 2; ++half) {
            #pragma unroll
            for (int bi = 0; bi < 4; ++bi) {
                float* rp = &red[(size_t)tid * 34 + bi * 8];
                float4 o1 = {acc[half * 4 + bi][0], acc[half * 4 + bi][1],
                             acc[half * 4 + bi][2], acc[half * 4 + bi][3]};
                float4 o2 = {acc[half * 4 + bi][4], acc[half * 4 + bi][5],
                             acc[half * 4 + bi][6], acc[half * 4 + bi][7]};
                *(float4*)rp = o1;
                *(float4*)(rp + 4) = o2;
            }
            __syncthreads();
            if ((cb >> 2) == half) {
                const int cbl = cb & 3;
                #pragma unroll
                for (int g = 0; g < 4; ++g) {
                    const int ttg = g * 4 + (chcm >> 3);
                    const int gj = chcm & 7;
                    float s = 0.0f;
                    #pragma unroll
                    for (int k2 = 0; k2 < 16; ++k2)
                        s += red[(size_t)(k2 * 16 + ttg) * 34 + cbl * 8 + gj];
                    gates[g] = s;
                }
            }
            __syncthreads();
        }

        // ---- cell update (thread-local c), h -> out[t]
        float ii = hsig(gi + gates[0]);
        float ff = hsig(gf + gates[1]);
        float gv = htanh(gg + gates[2]);
        float oo = hsig(go + gates[3]);
        creg = ff * creg + ii * gv;
        out[(size_t)t * BH + cell_h] = oo * htanh(creg);
    }
}

// ---------------------------------------------------------------------------
extern "C" void kernel_launch(void* const* d_in, const int* in_sizes, int n_in,
                              void* d_out, int out_size, void* d_ws, size_t ws_size,
                              hipStream_t stream) {
    const float* x  = (const float*)d_in[0];   // [T,B,D]
    const float* Wx = (const float*)d_in[1];   // [D,4H]
    const float* Wh = (const float*)d_in[2];   // [H,4H]
    const float* bs = (const float*)d_in[3];   // [4H]
    float* out = (float*)d_out;                // [T,B,H] — doubles as h history

    // ws layout (floats): Gx 33,554,432 | barrier (2 u32)
    float* Gx = (float*)d_ws;
    unsigned* bar = (unsigned*)(Gx + (size_t)MM * G4);

    zero_bar<<<dim3(1), dim3(64), 0, stream>>>(bar);

    // Gx = X @ Wx + b for all timesteps at once
    gx_gemm<<<dim3(G4 / 128, MM / 128), dim3(256), 0, stream>>>(x, Wx, bs, Gx);

    // all 128 recurrent steps in one plain-launch persistent kernel
    lstm_persist<<<dim3(NWG), dim3(256), 0, stream>>>(Gx, Wh, out, bar);
}

// Round 6
// 3838.206 us; speedup vs baseline: 1.1982x; 1.1982x over previous
//
#include <hip/hip_runtime.h>

// Problem constants: T=128, B=64, D=1024, H=1024. fp32 throughout (the
// recurrence is chaotic: per-step gate noise amplifies ~1e3x over 128 steps;
// fp32 order-noise lands at ~4e-3 absmax, bf16 would fail the 2e-2 gate).
#define TT 128
#define BB 64
#define DD 1024
#define HH 1024
#define G4 4096          // 4*H
#define MM (TT*BB)       // 8192 rows of X flattened
#define BH (BB*HH)       // 65536, one timestep of h/out

#define NWG 256          // persistent grid: exactly 1 block per CU

__device__ __forceinline__ float hsig(float x) {
    x += 0.5f;
    return fminf(fmaxf(x, 0.0f), 1.0f);
}
__device__ __forceinline__ float htanh(float x) {
    return fminf(fmaxf(x, -1.0f), 1.0f);
}

// ---------------------------------------------------------------------------
__global__ void zero_bar(unsigned* p) {
    p[threadIdx.x] = 0u;   // 512 words: flags[256] + rel + pad
}

// ---------------------------------------------------------------------------
// Gx[8192][4096] = X[8192][1024] @ Wx[1024][4096] + bias  (proven, ~810 us)
__global__ __launch_bounds__(256) void gx_gemm(const float* __restrict__ X,
                                               const float* __restrict__ W,
                                               const float* __restrict__ bias,
                                               float* __restrict__ C) {
    __shared__ float As[16][132];
    __shared__ float Bs[16][132];

    const int tid = threadIdx.x;
    const int tx = tid & 15;
    const int ty = tid >> 4;
    const int m0 = blockIdx.y * 128;
    const int n0 = blockIdx.x * 128;

    float acc[8][8] = {};
    float4 ra[2], rb[2];

    #pragma unroll
    for (int i = 0; i < 2; ++i) {
        int f4 = tid + i * 256;
        ra[i] = *(const float4*)(X + (size_t)(m0 + (f4 >> 2)) * DD + (f4 & 3) * 4);
        rb[i] = *(const float4*)(W + (size_t)(f4 >> 5) * G4 + n0 + (f4 & 31) * 4);
    }

    for (int k0 = 0; k0 < DD; k0 += 16) {
        #pragma unroll
        for (int i = 0; i < 2; ++i) {
            int f4 = tid + i * 256;
            int mi = f4 >> 2, kq = f4 & 3;
            As[kq * 4 + 0][mi] = ra[i].x;
            As[kq * 4 + 1][mi] = ra[i].y;
            As[kq * 4 + 2][mi] = ra[i].z;
            As[kq * 4 + 3][mi] = ra[i].w;
            *(float4*)&Bs[f4 >> 5][(f4 & 31) * 4] = rb[i];
        }
        __syncthreads();

        const int kn = (k0 + 16 < DD) ? (k0 + 16) : k0;
        #pragma unroll
        for (int i = 0; i < 2; ++i) {
            int f4 = tid + i * 256;
            ra[i] = *(const float4*)(X + (size_t)(m0 + (f4 >> 2)) * DD + kn + (f4 & 3) * 4);
            rb[i] = *(const float4*)(W + (size_t)(kn + (f4 >> 5)) * G4 + n0 + (f4 & 31) * 4);
        }

        #pragma unroll
        for (int kk = 0; kk < 16; ++kk) {
            float ar[8], br[8];
            *(float4*)&ar[0] = *(const float4*)&As[kk][ty * 4];
            *(float4*)&ar[4] = *(const float4*)&As[kk][64 + ty * 4];
            *(float4*)&br[0] = *(const float4*)&Bs[kk][tx * 4];
            *(float4*)&br[4] = *(const float4*)&Bs[kk][64 + tx * 4];
            #pragma unroll
            for (int i = 0; i < 8; ++i)
                #pragma unroll
                for (int j = 0; j < 8; ++j)
                    acc[i][j] += ar[i] * br[j];
        }
        __syncthreads();
    }

    float bl[8];
    *(float4*)&bl[0] = *(const float4*)(bias + n0 + tx * 4);
    *(float4*)&bl[4] = *(const float4*)(bias + n0 + 64 + tx * 4);
    #pragma unroll
    for (int i = 0; i < 8; ++i) {
        int mrow = m0 + ty * 4 + (i & 3) + 64 * (i >> 2);
        float* crow = C + (size_t)mrow * G4 + n0;
        float4 o1, o2;
        o1.x = acc[i][0] + bl[0]; o1.y = acc[i][1] + bl[1];
        o1.z = acc[i][2] + bl[2]; o1.w = acc[i][3] + bl[3];
        o2.x = acc[i][4] + bl[4]; o2.y = acc[i][5] + bl[5];
        o2.z = acc[i][6] + bl[6]; o2.w = acc[i][7] + bl[7];
        *(float4*)(crow + tx * 4) = o1;
        *(float4*)(crow + 64 + tx * 4) = o2;
    }
}

// ---------------------------------------------------------------------------
// Flag-array grid barrier: NO shared-address atomic contention.
// Each wg leader: release fence, store own flag; wg0's threads gather all
// flags in parallel, then publish `rel`; everyone acquires on `rel`.
// Residency: grid=256 = 1 block/CU, structurally co-resident.
__device__ __forceinline__ void gbar(unsigned* flags, unsigned* rel, unsigned target) {
    __syncthreads();
    const int tid = threadIdx.x;
    if (blockIdx.x == 0) {
        if (tid == 0) __threadfence();               // publish wg0's stores
        __syncthreads();
        if (tid > 0 && tid < NWG) {                  // gather wgs 1..255
            while (__hip_atomic_load(flags + tid, __ATOMIC_RELAXED,
                                     __HIP_MEMORY_SCOPE_AGENT) < target)
                __builtin_amdgcn_s_sleep(1);
        }
        __syncthreads();
        if (tid == 0) {
            __hip_atomic_store(rel, target, __ATOMIC_RELAXED,
                               __HIP_MEMORY_SCOPE_AGENT);
            __threadfence();                         // wg0 acquire side
        }
        __syncthreads();
    } else {
        if (tid == 0) {
            __threadfence();                         // publish this wg's stores
            __hip_atomic_store(flags + blockIdx.x, target, __ATOMIC_RELAXED,
                               __HIP_MEMORY_SCOPE_AGENT);
            while (__hip_atomic_load(rel, __ATOMIC_RELAXED,
                                     __HIP_MEMORY_SCOPE_AGENT) < target)
                __builtin_amdgcn_s_sleep(1);
            __threadfence();                         // acquire: inv L1/L2
        }
        __syncthreads();
    }
}

// ---------------------------------------------------------------------------
// Persistent recurrence, one barrier per step. Grid 256 wgs x 512 threads
// (8 waves/CU = 2/SIMD for latency hiding). wg = btile(8 b) x hct(32 hc),
// owns cells (8 b x 32 hc x 4 gates); c carried in a register all 128 steps.
// K=1024 split 32-way across threads (kc = tid>>4), LDS-reduced in-wg.
// hs is SKEWED (row stride 1152, +36 per 32-k chunk) so the 4 kc-groups of
// a wave read distinct bank quads -> conflict-free h loads.
__global__ __launch_bounds__(512) void lstm_persist(const float* __restrict__ Gx,
                                                    const float* __restrict__ Wh,
                                                    float* __restrict__ out,
                                                    unsigned* __restrict__ flags,
                                                    unsigned* __restrict__ rel) {
    // union: hs = [8 b][1152] = 9216 floats | red = [512 thr][34] = 17408
    __shared__ float smem[17408];
    float* hs  = smem;
    float* red = smem;

    const int tid = threadIdx.x;
    const int btile = blockIdx.x >> 5;     // 0..7
    const int hct   = blockIdx.x & 31;     // 0..31
    const int b0 = btile * 8;

    // matmul thread identity: kc = 32-k chunk, tt = 8 gate-cols
    const int kc = tid >> 4;               // 0..31
    const int tt = tid & 15;               // 0..15
    const int gate = tt >> 2;              // 0..3
    const int hq8  = (tt & 3) * 8;
    const float* wbase = Wh + (size_t)(kc * 32) * G4 + gate * HH + hct * 32 + hq8;

    // cell thread identity (threads 0..255; c lives in creg all steps)
    const bool cell_act = (tid < 256);
    const int cb   = (tid >> 5) & 7;       // 0..7 local b
    const int chcm = tid & 31;             // 0..31 local hc
    const size_t cell_g = (size_t)(b0 + cb) * G4 + hct * 32 + chcm;
    const size_t cell_h = (size_t)(b0 + cb) * HH + hct * 32 + chcm;
    float creg = 0.0f;

    // ---- t = 0: gates = Gx[0] (h0 = c0 = 0)
    if (cell_act) {
        const float* gr = Gx + cell_g;
        float ii = hsig(gr[0]);
        float gv = htanh(gr[2 * HH]);
        float oo = hsig(gr[3 * HH]);
        creg = ii * gv;
        out[cell_h] = oo * htanh(creg);
    }

    for (int t = 1; t < TT; ++t) {
        // prefetch this step's Gx gate values (read-only; overlaps barrier)
        float gi = 0.f, gf = 0.f, gg = 0.f, go = 0.f;
        if (cell_act) {
            const float* gr = Gx + (size_t)t * BB * G4 + cell_g;
            gi = gr[0];
            gf = gr[HH];
            gg = gr[2 * HH];
            go = gr[3 * HH];
        }

        gbar(flags, rel, (unsigned)t);     // h(t-1) visible; smem free

        // ---- stage h(t-1)[b0..b0+7][:] -> skewed hs
        const float* hprev = out + (size_t)(t - 1) * BH;
        #pragma unroll
        for (int i = 0; i < 4; ++i) {
            int idx = tid + i * 512;       // 0..2047
            int bi = idx >> 8;
            int q  = idx & 255;            // float4 index within row
            *(float4*)&hs[bi * 1152 + (q >> 3) * 36 + (q & 7) * 4] =
                *(const float4*)(hprev + (size_t)(b0 + bi) * HH + q * 4);
        }
        __syncthreads();

        // ---- FMA: acc[8 b][8 gc] over k in [kc*32, kc*32+32)
        float acc[8][8] = {};
        const float* wp = wbase;
        #pragma unroll 2
        for (int k4 = 0; k4 < 8; ++k4) {
            float4 hv[8];
            #pragma unroll
            for (int bi = 0; bi < 8; ++bi)
                hv[bi] = *(const float4*)&hs[bi * 1152 + kc * 36 + k4 * 4];
            #pragma unroll
            for (int j = 0; j < 4; ++j) {
                float4 w0 = *(const float4*)(wp);
                float4 w1 = *(const float4*)(wp + 4);
                wp += G4;
                #pragma unroll
                for (int bi = 0; bi < 8; ++bi) {
                    float h = (j == 0) ? hv[bi].x : (j == 1) ? hv[bi].y
                              : (j == 2) ? hv[bi].z : hv[bi].w;
                    acc[bi][0] += h * w0.x;
                    acc[bi][1] += h * w0.y;
                    acc[bi][2] += h * w0.z;
                    acc[bi][3] += h * w0.w;
                    acc[bi][4] += h * w1.x;
                    acc[bi][5] += h * w1.y;
                    acc[bi][6] += h * w1.z;
                    acc[bi][7] += h * w1.w;
                }
            }
        }
        __syncthreads();                   // hs dead; smem becomes red

        // ---- two half-reductions (b 0..3, then 4..7) across the 32 kc
        float gates[4] = {0.f, 0.f, 0.f, 0.f};
        #pragma unroll
        for (int half = 0; half < 2; ++half) {
            #pragma unroll
            for (int bi = 0; bi < 4; ++bi) {
                float* rp = &red[(size_t)tid * 34 + bi * 8];
                float4 o1 = {acc[half * 4 + bi][0], acc[half * 4 + bi][1],
                             acc[half * 4 + bi][2], acc[half * 4 + bi][3]};
                float4 o2 = {acc[half * 4 + bi][4], acc[half * 4 + bi][5],
                             acc[half * 4 + bi][6], acc[half * 4 + bi][7]};
                *(float4*)rp = o1;
                *(float4*)(rp + 4) = o2;
            }
            __syncthreads();
            if (cell_act && ((cb >> 2) == half)) {
                const int cbl = cb & 3;
                #pragma unroll
                for (int g = 0; g < 4; ++g) {
                    const int ttg = g * 4 + (chcm >> 3);
                    const int gj = chcm & 7;
                    float s = 0.0f;
                    #pragma unroll
                    for (int k2 = 0; k2 < 32; ++k2)
                        s += red[(size_t)(k2 * 16 + ttg) * 34 + cbl * 8 + gj];
                    gates[g] = s;
                }
            }
            __syncthreads();
        }

        // ---- cell update (thread-local c), h -> out[t]
        if (cell_act) {
            float ii = hsig(gi + gates[0]);
            float ff = hsig(gf + gates[1]);
            float gv = htanh(gg + gates[2]);
            float oo = hsig(go + gates[3]);
            creg = ff * creg + ii * gv;
            out[(size_t)t * BH + cell_h] = oo * htanh(creg);
        }
    }
}

// ---------------------------------------------------------------------------
extern "C" void kernel_launch(void* const* d_in, const int* in_sizes, int n_in,
                              void* d_out, int out_size, void* d_ws, size_t ws_size,
                              hipStream_t stream) {
    const float* x  = (const float*)d_in[0];   // [T,B,D]
    const float* Wx = (const float*)d_in[1];   // [D,4H]
    const float* Wh = (const float*)d_in[2];   // [H,4H]
    const float* bs = (const float*)d_in[3];   // [4H]
    float* out = (float*)d_out;                // [T,B,H] — doubles as h history

    // ws layout (floats): Gx 33,554,432 | bar: flags[256] + rel (512 u32)
    float* Gx = (float*)d_ws;
    unsigned* bar = (unsigned*)(Gx + (size_t)MM * G4);
    unsigned* flags = bar;
    unsigned* rel = bar + NWG;

    zero_bar<<<dim3(1), dim3(512), 0, stream>>>(bar);

    // Gx = X @ Wx + b for all timesteps at once
    gx_gemm<<<dim3(G4 / 128, MM / 128), dim3(256), 0, stream>>>(x, Wx, bs, Gx);

    // all 128 recurrent steps in one plain-launch persistent kernel
    lstm_persist<<<dim3(NWG), dim3(512), 0, stream>>>(Gx, Wh, out, flags, rel);
}

// Round 7
// 2647.835 us; speedup vs baseline: 1.7368x; 1.4496x over previous
//
#include <hip/hip_runtime.h>

// Problem constants: T=128, B=64, D=1024, H=1024. fp32 throughout (the
// recurrence is chaotic: per-step gate noise amplifies ~1e3x over 128 steps;
// fp32 order-noise lands at ~4e-3 absmax, bf16 would fail the 2e-2 gate).
#define TT 128
#define BB 64
#define DD 1024
#define HH 1024
#define G4 4096          // 4*H
#define MM (TT*BB)       // 8192 rows of X flattened
#define BH (BB*HH)       // 65536, one timestep of h/out

#define NWG 256          // persistent grid: exactly 1 block per CU

__device__ __forceinline__ float hsig(float x) {
    x += 0.5f;
    return fminf(fmaxf(x, 0.0f), 1.0f);
}
__device__ __forceinline__ float htanh(float x) {
    return fminf(fmaxf(x, -1.0f), 1.0f);
}

// ---------------------------------------------------------------------------
__global__ void zero_bar(unsigned* p) {
    p[threadIdx.x] = 0u;   // flags[256]
}

// ---------------------------------------------------------------------------
// Gx[8192][4096] = X[8192][1024] @ Wx[1024][4096] + bias  (proven, ~810 us)
__global__ __launch_bounds__(256) void gx_gemm(const float* __restrict__ X,
                                               const float* __restrict__ W,
                                               const float* __restrict__ bias,
                                               float* __restrict__ C) {
    __shared__ float As[16][132];
    __shared__ float Bs[16][132];

    const int tid = threadIdx.x;
    const int tx = tid & 15;
    const int ty = tid >> 4;
    const int m0 = blockIdx.y * 128;
    const int n0 = blockIdx.x * 128;

    float acc[8][8] = {};
    float4 ra[2], rb[2];

    #pragma unroll
    for (int i = 0; i < 2; ++i) {
        int f4 = tid + i * 256;
        ra[i] = *(const float4*)(X + (size_t)(m0 + (f4 >> 2)) * DD + (f4 & 3) * 4);
        rb[i] = *(const float4*)(W + (size_t)(f4 >> 5) * G4 + n0 + (f4 & 31) * 4);
    }

    for (int k0 = 0; k0 < DD; k0 += 16) {
        #pragma unroll
        for (int i = 0; i < 2; ++i) {
            int f4 = tid + i * 256;
            int mi = f4 >> 2, kq = f4 & 3;
            As[kq * 4 + 0][mi] = ra[i].x;
            As[kq * 4 + 1][mi] = ra[i].y;
            As[kq * 4 + 2][mi] = ra[i].z;
            As[kq * 4 + 3][mi] = ra[i].w;
            *(float4*)&Bs[f4 >> 5][(f4 & 31) * 4] = rb[i];
        }
        __syncthreads();

        const int kn = (k0 + 16 < DD) ? (k0 + 16) : k0;
        #pragma unroll
        for (int i = 0; i < 2; ++i) {
            int f4 = tid + i * 256;
            ra[i] = *(const float4*)(X + (size_t)(m0 + (f4 >> 2)) * DD + kn + (f4 & 3) * 4);
            rb[i] = *(const float4*)(W + (size_t)(kn + (f4 >> 5)) * G4 + n0 + (f4 & 31) * 4);
        }

        #pragma unroll
        for (int kk = 0; kk < 16; ++kk) {
            float ar[8], br[8];
            *(float4*)&ar[0] = *(const float4*)&As[kk][ty * 4];
            *(float4*)&ar[4] = *(const float4*)&As[kk][64 + ty * 4];
            *(float4*)&br[0] = *(const float4*)&Bs[kk][tx * 4];
            *(float4*)&br[4] = *(const float4*)&Bs[kk][64 + tx * 4];
            #pragma unroll
            for (int i = 0; i < 8; ++i)
                #pragma unroll
                for (int j = 0; j < 8; ++j)
                    acc[i][j] += ar[i] * br[j];
        }
        __syncthreads();
    }

    float bl[8];
    *(float4*)&bl[0] = *(const float4*)(bias + n0 + tx * 4);
    *(float4*)&bl[4] = *(const float4*)(bias + n0 + 64 + tx * 4);
    #pragma unroll
    for (int i = 0; i < 8; ++i) {
        int mrow = m0 + ty * 4 + (i & 3) + 64 * (i >> 2);
        float* crow = C + (size_t)mrow * G4 + n0;
        float4 o1, o2;
        o1.x = acc[i][0] + bl[0]; o1.y = acc[i][1] + bl[1];
        o1.z = acc[i][2] + bl[2]; o1.w = acc[i][3] + bl[3];
        o2.x = acc[i][4] + bl[4]; o2.y = acc[i][5] + bl[5];
        o2.z = acc[i][6] + bl[6]; o2.w = acc[i][7] + bl[7];
        *(float4*)(crow + tx * 4) = o1;
        *(float4*)(crow + 64 + tx * 4) = o2;
    }
}

// ---------------------------------------------------------------------------
// Persistent recurrence. FENCE-FREE cross-wg h exchange: all h values cross
// wg boundaries as dword agent-scope relaxed atomics (sc0 sc1 in the
// instruction: bypass L1/L2, served by Infinity Cache). No __threadfence in
// the loop -> L2 is NEVER invalidated -> Wh stays L2-resident (2 MB/XCD
// under bx%8 = hct%8 round-robin heuristic; correctness is placement-free).
// Sync domain: only the 32 wgs sharing a btile (the h producers/consumers
// of those 8 batch rows) — per-wg flags, direct 32-way all-gather.
// Ordering: h atomic stores -> s_waitcnt vmcnt(0) (per wave) ->
// __syncthreads -> flag store.
__global__ __launch_bounds__(512) void lstm_persist(const float* __restrict__ Gx,
                                                    const float* __restrict__ Wh,
                                                    float* __restrict__ out,
                                                    unsigned* __restrict__ flags) {
    // union: hs = [8 b][1152] = 9216 | red = [32 idx][521 tid-col] = 16672
    __shared__ float smem[16672];
    float* hs  = smem;
    float* red = smem;

    const int tid = threadIdx.x;
    const int btile = blockIdx.x >> 5;     // 0..7
    const int hct   = blockIdx.x & 31;     // 0..31
    const int b0 = btile * 8;

    // matmul thread identity: kc = 32-k chunk, tt = 8 gate-cols
    const int kc = tid >> 4;               // 0..31
    const int tt = tid & 15;               // 0..15
    const int gate = tt >> 2;              // 0..3
    const int hq8  = (tt & 3) * 8;
    const float* wbase = Wh + (size_t)(kc * 32) * G4 + gate * HH + hct * 32 + hq8;

    // cell thread identity (threads 0..255; c lives in creg all steps)
    const bool cell_act = (tid < 256);
    const int cb   = (tid >> 5) & 7;       // 0..7 local b
    const int chcm = tid & 31;             // 0..31 local hc
    const size_t cell_g = (size_t)(b0 + cb) * G4 + hct * 32 + chcm;
    const size_t cell_h = (size_t)(b0 + cb) * HH + hct * 32 + chcm;
    float creg = 0.0f;

    // reduction identities
    const int half_id = cb >> 2;
    const int ridx = (cb & 3) * 8 + (chcm & 7);   // value index 0..31

    unsigned* gflags = flags + btile * 32; // this btile group's 32 flags

    // ---- t = 0: gates = Gx[0] (h0 = c0 = 0); publish h(0) through IC
    if (cell_act) {
        const float* gr = Gx + cell_g;
        float ii = hsig(gr[0]);
        float gv = htanh(gr[2 * HH]);
        float oo = hsig(gr[3 * HH]);
        creg = ii * gv;
        __hip_atomic_store(out + cell_h, oo * htanh(creg),
                           __ATOMIC_RELAXED, __HIP_MEMORY_SCOPE_AGENT);
    }
    asm volatile("s_waitcnt vmcnt(0)" ::: "memory");
    __syncthreads();
    if (tid == 0)
        __hip_atomic_store(gflags + hct, 1u, __ATOMIC_RELAXED,
                           __HIP_MEMORY_SCOPE_AGENT);

    for (int t = 1; t < TT; ++t) {
        // prefetch this step's Gx gate values (own data; overlaps the wait)
        float gi = 0.f, gf = 0.f, gg = 0.f, go = 0.f;
        if (cell_act) {
            const float* gr = Gx + (size_t)t * BB * G4 + cell_g;
            gi = gr[0];
            gf = gr[HH];
            gg = gr[2 * HH];
            go = gr[3 * HH];
        }

        // ---- group barrier: wait for all 32 producers of h(t-1)
        if (tid < 32) {
            while (__hip_atomic_load(gflags + tid, __ATOMIC_RELAXED,
                                     __HIP_MEMORY_SCOPE_AGENT) < (unsigned)t)
                __builtin_amdgcn_s_sleep(1);
        }
        __syncthreads();

        // ---- stage h(t-1)[b0..b0+7][:] -> skewed hs (IC-scope dword loads)
        const float* hprev = out + (size_t)(t - 1) * BH;
        #pragma unroll
        for (int i = 0; i < 16; ++i) {
            int idx = tid + i * 512;       // 0..8191
            int bi = idx >> 10;
            int q  = idx & 1023;
            float v = __hip_atomic_load(hprev + (size_t)(b0 + bi) * HH + q,
                                        __ATOMIC_RELAXED, __HIP_MEMORY_SCOPE_AGENT);
            hs[bi * 1152 + (q >> 5) * 36 + (q & 31)] = v;
        }
        __syncthreads();

        // ---- FMA: acc[8 b][8 gc] over k in [kc*32, kc*32+32)
        float acc[8][8] = {};
        const float* wp = wbase;
        #pragma unroll 2
        for (int k4 = 0; k4 < 8; ++k4) {
            float4 hv[8];
            #pragma unroll
            for (int bi = 0; bi < 8; ++bi)
                hv[bi] = *(const float4*)&hs[bi * 1152 + kc * 36 + k4 * 4];
            #pragma unroll
            for (int j = 0; j < 4; ++j) {
                float4 w0 = *(const float4*)(wp);
                float4 w1 = *(const float4*)(wp + 4);
                wp += G4;
                #pragma unroll
                for (int bi = 0; bi < 8; ++bi) {
                    float h = (j == 0) ? hv[bi].x : (j == 1) ? hv[bi].y
                              : (j == 2) ? hv[bi].z : hv[bi].w;
                    acc[bi][0] += h * w0.x;
                    acc[bi][1] += h * w0.y;
                    acc[bi][2] += h * w0.z;
                    acc[bi][3] += h * w0.w;
                    acc[bi][4] += h * w1.x;
                    acc[bi][5] += h * w1.y;
                    acc[bi][6] += h * w1.z;
                    acc[bi][7] += h * w1.w;
                }
            }
        }
        __syncthreads();                   // hs dead; smem becomes red

        // ---- two half-reductions, conflict-free layout red[value][tid]
        float gates[4] = {0.f, 0.f, 0.f, 0.f};
        #pragma unroll
        for (int half = 0; half < 2; ++half) {
            #pragma unroll
            for (int bi = 0; bi < 4; ++bi)
                #pragma unroll
                for (int j = 0; j < 8; ++j)
                    red[(size_t)(bi * 8 + j) * 521 + tid] = acc[half * 4 + bi][j];
            __syncthreads();
            if (cell_act && (half_id == half)) {
                #pragma unroll
                for (int g = 0; g < 4; ++g) {
                    const int wt = g * 4 + (chcm >> 3);   // writer tt
                    float s = 0.0f;
                    #pragma unroll
                    for (int k2 = 0; k2 < 32; ++k2)
                        s += red[(size_t)ridx * 521 + k2 * 16 + wt];
                    gates[g] = s;
                }
            }
            __syncthreads();
        }

        // ---- cell update (thread-local c); publish h through IC
        if (cell_act) {
            float ii = hsig(gi + gates[0]);
            float ff = hsig(gf + gates[1]);
            float gv = htanh(gg + gates[2]);
            float oo = hsig(go + gates[3]);
            creg = ff * creg + ii * gv;
            __hip_atomic_store(out + (size_t)t * BH + cell_h, oo * htanh(creg),
                               __ATOMIC_RELAXED, __HIP_MEMORY_SCOPE_AGENT);
        }
        asm volatile("s_waitcnt vmcnt(0)" ::: "memory");
        __syncthreads();
        if (tid == 0)
            __hip_atomic_store(gflags + hct, (unsigned)(t + 1),
                               __ATOMIC_RELAXED, __HIP_MEMORY_SCOPE_AGENT);
    }
}

// ---------------------------------------------------------------------------
extern "C" void kernel_launch(void* const* d_in, const int* in_sizes, int n_in,
                              void* d_out, int out_size, void* d_ws, size_t ws_size,
                              hipStream_t stream) {
    const float* x  = (const float*)d_in[0];   // [T,B,D]
    const float* Wx = (const float*)d_in[1];   // [D,4H]
    const float* Wh = (const float*)d_in[2];   // [H,4H]
    const float* bs = (const float*)d_in[3];   // [4H]
    float* out = (float*)d_out;                // [T,B,H] — doubles as h history

    // ws layout (floats): Gx 33,554,432 | flags (256 u32)
    float* Gx = (float*)d_ws;
    unsigned* flags = (unsigned*)(Gx + (size_t)MM * G4);

    zero_bar<<<dim3(1), dim3(256), 0, stream>>>(flags);

    // Gx = X @ Wx + b for all timesteps at once
    gx_gemm<<<dim3(G4 / 128, MM / 128), dim3(256), 0, stream>>>(x, Wx, bs, Gx);

    // all 128 recurrent steps in one plain-launch persistent kernel
    lstm_persist<<<dim3(NWG), dim3(512), 0, stream>>>(Gx, Wh, out, flags);
}